// Round 8
// baseline (5914.080 us; speedup 1.0000x reference)
//
#include <hip/hip_runtime.h>
#include <hip/hip_bf16.h>

#define BB 8
#define NN 4096
#define FF 64
#define HH 128
#define KNN 16

// ---- reference-matching arithmetic (XLA-CPU style: FMA-contracted dot/sq) ----
__device__ __forceinline__ float sq3(float x, float y, float z) {
    return fmaf(z, z, fmaf(y, y, __fmul_rn(x, x)));
}
// dist2 = (sq_n + sq_m) - 2*dot, dot = fma chain
__device__ __forceinline__ float dist2f(float px, float py, float pz, float psq, float4 cc) {
    float t = fmaf(pz, cc.z, fmaf(py, cc.y, __fmul_rn(px, cc.x)));
    return __fsub_rn(__fadd_rn(psq, cc.w), __fmul_rn(2.0f, t));
}

// ---------------- Kernel 1: pack coords + sq norm, compute per-batch center ----------------
extern "C" __global__ __launch_bounds__(256)
void k_prep(const float* __restrict__ coords, float4* __restrict__ coords4, float* __restrict__ center) {
    const int b = blockIdx.x, tid = threadIdx.x;
    __shared__ float rx[256], ry[256], rz[256];
    float sx = 0.f, sy = 0.f, sz = 0.f;
    for (int n = tid; n < NN; n += 256) {
        const float* c = coords + (size_t)(b * NN + n) * 3;
        float x = c[0], y = c[1], z = c[2];
        coords4[b * NN + n] = make_float4(x, y, z, sq3(x, y, z));
        sx += x; sy += y; sz += z;
    }
    rx[tid] = sx; ry[tid] = sy; rz[tid] = sz;
    __syncthreads();
    for (int s = 128; s > 0; s >>= 1) {
        if (tid < s) { rx[tid] += rx[tid + s]; ry[tid] += ry[tid + s]; rz[tid] += rz[tid + s]; }
        __syncthreads();
    }
    if (tid == 0) {
        center[b * 4 + 0] = rx[0] * (1.0f / NN);
        center[b * 4 + 1] = ry[0] * (1.0f / NN);
        center[b * 4 + 2] = rz[0] * (1.0f / NN);
    }
}

// Jacobi rotation on symmetric 3x3 (exact rotations, division-safe).
#define JROT(app, aqq, apq, arp, arq, vp0, vp1, vp2, vq0, vq1, vq2) { \
    float tau_ = (aqq - app) / (2.0f * apq); \
    float tt_ = copysignf(1.0f, tau_) / (fabsf(tau_) + sqrtf(1.0f + tau_ * tau_)); \
    if (apq == 0.0f) tt_ = 0.0f; \
    float cc_ = 1.0f / sqrtf(1.0f + tt_ * tt_); \
    float ss_ = tt_ * cc_; \
    float app_n = cc_*cc_*app - 2.0f*cc_*ss_*apq + ss_*ss_*aqq; \
    float aqq_n = ss_*ss_*app + 2.0f*cc_*ss_*apq + cc_*cc_*aqq; \
    float apq_n = cc_*ss_*(app - aqq) + (cc_*cc_ - ss_*ss_)*apq; \
    float arp_n = cc_*arp - ss_*arq; \
    float arq_n = ss_*arp + cc_*arq; \
    app = app_n; aqq = aqq_n; apq = apq_n; arp = arp_n; arq = arq_n; \
    float t0_ = cc_*vp0 - ss_*vq0, t1_ = cc_*vp1 - ss_*vq1, t2_ = cc_*vp2 - ss_*vq2; \
    vq0 = ss_*vp0 + cc_*vq0; vq1 = ss_*vp1 + cc_*vq1; vq2 = ss_*vp2 + cc_*vq2; \
    vp0 = t0_; vp1 = t1_; vp2 = t2_; }

#define SWAPF(a, b) { float sw_ = a; a = b; b = sw_; }

// Bitonic sort 16 floats ascending (80 compare-exchanges, exact multiset op).
__device__ __forceinline__ void sort16(float (&d)[16]) {
#pragma unroll
    for (int k = 2; k <= 16; k <<= 1) {
#pragma unroll
        for (int j = k >> 1; j > 0; j >>= 1) {
#pragma unroll
            for (int i = 0; i < 16; i++) {
                int l = i ^ j;
                if (l > i) {
                    if ((i & k) == 0) {
                        float mn = fminf(d[i], d[l]);
                        d[l] = fmaxf(d[i], d[l]);
                        d[i] = mn;
                    } else {
                        float mx = fmaxf(d[i], d[l]);
                        d[l] = fminf(d[i], d[l]);
                        d[i] = mx;
                    }
                }
            }
        }
    }
}

// dk (asc) + d (asc) -> dk = 16 smallest of the 32, ascending (Batcher halver + clean).
__device__ __forceinline__ void merge16(float (&dk)[16], const float (&d)[16]) {
    float t[16];
#pragma unroll
    for (int i = 0; i < 16; i++) t[i] = fminf(dk[i], d[15 - i]);   // bitonic, holds lowest 16
#pragma unroll
    for (int j = 8; j > 0; j >>= 1) {
#pragma unroll
        for (int i = 0; i < 16; i++) {
            int l = i ^ j;
            if (l > i) {
                float mn = fminf(t[i], t[l]);
                t[l] = fmaxf(t[i], t[l]);
                t[i] = mn;
            }
        }
    }
#pragma unroll
    for (int i = 0; i < 16; i++) dk[i] = t[i];
}

// ---------------- Kernel 2: kNN + local geometry + non-MLP output channels ----------------
// 1024 blocks x 256 threads. Block: batch b = blk>>7, 32-point chunk (blk&127).
// Thread: point = chunk*32 + (tid&31), candidate-eighth h = tid>>5 (512 candidates each).
extern "C" __global__ __launch_bounds__(256, 4)
void k_knn(const float4* __restrict__ coords4, const float* __restrict__ center,
           float* __restrict__ invar, float* __restrict__ out) {
    const int blk = blockIdx.x;
    const int b = blk >> 7;
    const int chunk = blk & 127;
    const int tid = threadIdx.x;
    const int pid = tid & 31;
    const int h = tid >> 5;
    const int n = chunk * 32 + pid;
    const float4* __restrict__ C = coords4 + b * NN;

    __shared__ __align__(16) float4 tile[512];    // 64 cands per eighth, 8 KB
    __shared__ int ilist[256 * 24];               // per (point,eighth): 15 strict + 8 tie + pad (24 KB)
    __shared__ int cnts[256];                     // packed cs | ct<<8
    float* mb = (float*)ilist;                    // merge buffer (256*17 floats), lifetime-disjoint

    float4 me = C[n];
    const float px = me.x, py = me.y, pz = me.z, psq = me.w;
    const float INF = __builtin_inff();

    // ---- pass 1: per-eighth sorted top-16 values via batch-sort + network merge ----
    float dk[KNN];
#pragma unroll
    for (int i = 0; i < KNN; i++) dk[i] = INF;

    for (int r = 0; r < 8; r++) {
        __syncthreads();
#pragma unroll
        for (int e = tid; e < 512; e += 256) {
            int seg = e >> 6, idx = e & 63;
            tile[e] = C[seg * 512 + r * 64 + idx];
        }
        __syncthreads();
        const float4* T = &tile[h * 64];
        const int selfj = n - (h * 512 + r * 64);   // in [0,64) iff diagonal in this slice
#pragma unroll
        for (int bt = 0; bt < 4; bt++) {
            float d[16];
#pragma unroll
            for (int i = 0; i < 16; i++) {
                float4 cc = T[bt * 16 + i];          // near-uniform -> LDS broadcast
                float dd = dist2f(px, py, pz, psq, cc);
                d[i] = (bt * 16 + i) == selfj ? INF : dd;
            }
            sort16(d);
            merge16(dk, d);
        }
    }

    // ---- symmetric 8-way merge: every thread merges its 7 partners' sorted-16 ----
    __syncthreads();
#pragma unroll
    for (int i = 0; i < KNN; i++) mb[tid * 17 + i] = dk[i];
    __syncthreads();
#pragma unroll
    for (int p = 1; p < 8; p++) {
        const int partner = (((h + p) & 7) << 5) + pid;
        float o[16];
#pragma unroll
        for (int i = 0; i < KNN; i++) o[i] = mb[partner * 17 + i];
        merge16(dk, o);
    }
    const float d15 = dk[15];

    // ---- pass 2: per-eighth index collection (strict < d15; ties == d15, index order) ----
    int cs = 0, ct = 0;
    const int lbase = (pid * 8 + h) * 24;
    for (int r = 0; r < 8; r++) {
        __syncthreads();
#pragma unroll
        for (int e = tid; e < 512; e += 256) {
            int seg = e >> 6, idx = e & 63;
            tile[e] = C[seg * 512 + r * 64 + idx];
        }
        __syncthreads();
        const float4* T = &tile[h * 64];
        const int base = h * 512 + r * 64;
#pragma unroll 4
        for (int j = 0; j < 64; j++) {
            float4 cc = T[j];
            float d = dist2f(px, py, pz, psq, cc);   // bitwise identical to pass 1
            int g = base + j;
            if (g != n && d <= d15) {
                if (d < d15) {
                    if (cs < 15) ilist[lbase + cs] = g;
                    cs++;
                } else if (ct < 8) {
                    ilist[lbase + 15 + ct] = g;
                    ct++;
                }
            }
        }
    }
    cnts[pid * 8 + h] = (cs & 0xff) | (ct << 8);
    __syncthreads();

    if (h != 0) return;   // first 32 threads handle the 32 points' epilogue

    // ---- assemble exactly 16 neighbor ids: stricts (segment order = index order), then ties ----
    int s[8], t8[8], sb[8], tb[8], cum[8], tcum[8];
#pragma unroll
    for (int q = 0; q < 8; q++) {
        int cp = cnts[pid * 8 + q];
        s[q] = cp & 0xff; t8[q] = cp >> 8;
        sb[q] = (pid * 8 + q) * 24; tb[q] = sb[q] + 15;
    }
    cum[0] = s[0]; tcum[0] = t8[0];
#pragma unroll
    for (int q = 1; q < 8; q++) { cum[q] = cum[q - 1] + s[q]; tcum[q] = tcum[q - 1] + t8[q]; }

    float cxx = 0.f, cxy = 0.f, cxz = 0.f, cyy = 0.f, cyz = 0.f, czz = 0.f, radsum = 0.f;
#pragma unroll
    for (int j = 0; j < KNN; j++) {
        int addr = sb[0] + j;
#pragma unroll
        for (int q = 1; q < 8; q++)
            if (j >= cum[q - 1]) addr = sb[q] + (j - cum[q - 1]);
        int jt = j - cum[7];
        if (j >= cum[7]) addr = tb[0] + jt;
#pragma unroll
        for (int q = 1; q < 8; q++)
            if (j >= cum[7] && jt >= tcum[q - 1]) addr = tb[q] + (jt - tcum[q - 1]);
        int id = ilist[addr];
        float4 cc = C[id];
        float rx = __fsub_rn(cc.x, px), ry = __fsub_rn(cc.y, py), rz = __fsub_rn(cc.z, pz);
        cxx = __fadd_rn(cxx, __fmul_rn(rx, rx));
        cxy = __fadd_rn(cxy, __fmul_rn(rx, ry));
        cxz = __fadd_rn(cxz, __fmul_rn(rx, rz));
        cyy = __fadd_rn(cyy, __fmul_rn(ry, ry));
        cyz = __fadd_rn(cyz, __fmul_rn(ry, rz));
        czz = __fadd_rn(czz, __fmul_rn(rz, rz));
        float rr = __fadd_rn(__fadd_rn(__fmul_rn(rx, rx), __fmul_rn(ry, ry)), __fmul_rn(rz, rz));
        radsum = __fadd_rn(radsum, sqrtf(rr));
    }
    const float inv_k = 1.0f / KNN;  // exact power of two
    float a00 = cxx * inv_k, a01 = cxy * inv_k, a02 = cxz * inv_k;
    float a11 = cyy * inv_k, a12 = cyz * inv_k, a22 = czz * inv_k;

    // ---- Jacobi eigensolver, 6 cyclic sweeps ----
    float V00 = 1.f, V01 = 0.f, V02 = 0.f;
    float V10 = 0.f, V11 = 1.f, V12 = 0.f;
    float V20 = 0.f, V21 = 0.f, V22 = 1.f;
    for (int sweep = 0; sweep < 6; sweep++) {
        JROT(a00, a11, a01, a02, a12, V00, V10, V20, V01, V11, V21);
        JROT(a00, a22, a02, a01, a12, V00, V10, V20, V02, V12, V22);
        JROT(a11, a22, a12, a01, a02, V01, V11, V21, V02, V12, V22);
    }
    float e0 = a00, e1 = a11, e2 = a22;
    float x0 = V00, y0 = V10, z0 = V20;
    float x1 = V01, y1 = V11, z1 = V21;
    float x2 = V02, y2 = V12, z2 = V22;
    if (e0 > e1) { SWAPF(e0, e1); SWAPF(x0, x1); SWAPF(y0, y1); SWAPF(z0, z1); }
    if (e1 > e2) { SWAPF(e1, e2); SWAPF(x1, x2); SWAPF(y1, y2); SWAPF(z1, z2); }
    if (e0 > e1) { SWAPF(e0, e1); SWAPF(x0, x1); SWAPF(y0, y1); SWAPF(z0, z1); }

    // ---- orient + normalize normal (col 0 = smallest eigenvalue) ----
    float cx = center[b * 4 + 0], cy = center[b * 4 + 1], cz = center[b * 4 + 2];
    float ox = __fsub_rn(px, cx), oy = __fsub_rn(py, cy), oz = __fsub_rn(pz, cz);
    float dt = __fadd_rn(__fadd_rn(__fmul_rn(x0, ox), __fmul_rn(y0, oy)), __fmul_rn(z0, oz));
    float sgn = (dt >= 0.0f) ? 1.0f : -1.0f;
    x0 *= sgn; y0 *= sgn; z0 *= sgn;
    float nrm = sqrtf(__fadd_rn(__fadd_rn(__fmul_rn(x0, x0), __fmul_rn(y0, y0)), __fmul_rn(z0, z0)));
    float den = fmaxf(nrm, 1e-6f);
    x0 = x0 / den; y0 = y0 / den; z0 = z0 / den;

    // ---- invariants -> ws ----
    float radius = radsum * inv_k;
    float crad = sqrtf(__fadd_rn(__fadd_rn(__fmul_rn(ox, ox), __fmul_rn(oy, oy)), __fmul_rn(oz, oz)));
    float esum = fmaxf(__fadd_rn(__fadd_rn(e0, e1), e2), 1e-6f);
    float dom = e2 / esum;
    float* ip = invar + (size_t)(b * NN + n) * 8;
    ip[0] = e0; ip[1] = e1; ip[2] = e2; ip[3] = radius; ip[4] = crad; ip[5] = dom;
    ip[6] = 0.f; ip[7] = 0.f;

    // ---- output channels (f32). ch0 placeholder, overwritten by k_mlp ----
    float pd = __fadd_rn(__fadd_rn(__fmul_rn(px, x0), __fmul_rn(py, y0)), __fmul_rn(pz, z0));
    float4* o = (float4*)(out + (size_t)(b * NN + n) * 16);
    o[0] = make_float4(0.0f, x0, y0, -z0);
    o[1] = make_float4(-pd, x0, y0, z0);
    o[2] = make_float4(0.0f, 0.0f, 0.0f, px);
    o[3] = make_float4(py, pz, 1.0f, 0.0f);
}

// ---------------- Kernel 3: fused MLPs ----------------
__device__ __forceinline__ float gelu_exact(float x) {
    return 0.5f * x * (1.0f + erff(x * 0.70710678118654752440f));
}

// Small-K GEMM (K=6).
template <int KDIM, int LDA>
__device__ __forceinline__ void gemm_small(const float* __restrict__ A, const float* __restrict__ W,
                                           const float* __restrict__ bias, int p0, int c0, float acc[4][4]) {
    float4 bb = *(const float4*)(bias + c0);
#pragma unroll
    for (int i = 0; i < 4; i++) { acc[i][0] = bb.x; acc[i][1] = bb.y; acc[i][2] = bb.z; acc[i][3] = bb.w; }
#pragma unroll
    for (int k = 0; k < KDIM; k++) {
        float4 w = *(const float4*)(W + k * HH + c0);
#pragma unroll
        for (int i = 0; i < 4; i++) {
            float a = A[(p0 + i) * LDA + k];
            acc[i][0] = fmaf(a, w.x, acc[i][0]);
            acc[i][1] = fmaf(a, w.y, acc[i][1]);
            acc[i][2] = fmaf(a, w.z, acc[i][2]);
            acc[i][3] = fmaf(a, w.w, acc[i][3]);
        }
    }
}

// K%8==0 GEMM. Single-buffered chunk-8: 8 independent W loads issued together
// (latency amortized 8x), aligned float4 A reads, 128 straight-line FMAs.
// NO double-buffer: a 2-deep prefetch spilled to scratch (R7: FETCH 6MB->10.5GB).
// Accumulation order: ascending k per output (bitwise identical to gemm_small).
template <int KDIM, int LDA>
__device__ __forceinline__ void gemm_c8(const float* __restrict__ A, const float* __restrict__ W,
                                        const float* __restrict__ bias, int p0, int c0, float acc[4][4]) {
    static_assert(KDIM % 8 == 0, "KDIM must be a multiple of 8");
    float4 bb = *(const float4*)(bias + c0);
#pragma unroll
    for (int i = 0; i < 4; i++) { acc[i][0] = bb.x; acc[i][1] = bb.y; acc[i][2] = bb.z; acc[i][3] = bb.w; }

#pragma unroll
    for (int kk = 0; kk < KDIM; kk += 8) {
        const float* Wk = W + kk * HH + c0;
        float4 w0 = *(const float4*)(Wk + 0 * HH);
        float4 w1 = *(const float4*)(Wk + 1 * HH);
        float4 w2 = *(const float4*)(Wk + 2 * HH);
        float4 w3 = *(const float4*)(Wk + 3 * HH);
        float4 w4 = *(const float4*)(Wk + 4 * HH);
        float4 w5 = *(const float4*)(Wk + 5 * HH);
        float4 w6 = *(const float4*)(Wk + 6 * HH);
        float4 w7 = *(const float4*)(Wk + 7 * HH);
#pragma unroll
        for (int r = 0; r < 4; r++) {
            const float* Ar = A + (p0 + r) * LDA + kk;
            float4 t0 = *(const float4*)(Ar);
            float4 t1 = *(const float4*)(Ar + 4);
            acc[r][0] = fmaf(t0.x, w0.x, acc[r][0]);
            acc[r][1] = fmaf(t0.x, w0.y, acc[r][1]);
            acc[r][2] = fmaf(t0.x, w0.z, acc[r][2]);
            acc[r][3] = fmaf(t0.x, w0.w, acc[r][3]);
            acc[r][0] = fmaf(t0.y, w1.x, acc[r][0]);
            acc[r][1] = fmaf(t0.y, w1.y, acc[r][1]);
            acc[r][2] = fmaf(t0.y, w1.z, acc[r][2]);
            acc[r][3] = fmaf(t0.y, w1.w, acc[r][3]);
            acc[r][0] = fmaf(t0.z, w2.x, acc[r][0]);
            acc[r][1] = fmaf(t0.z, w2.y, acc[r][1]);
            acc[r][2] = fmaf(t0.z, w2.z, acc[r][2]);
            acc[r][3] = fmaf(t0.z, w2.w, acc[r][3]);
            acc[r][0] = fmaf(t0.w, w3.x, acc[r][0]);
            acc[r][1] = fmaf(t0.w, w3.y, acc[r][1]);
            acc[r][2] = fmaf(t0.w, w3.z, acc[r][2]);
            acc[r][3] = fmaf(t0.w, w3.w, acc[r][3]);
            acc[r][0] = fmaf(t1.x, w4.x, acc[r][0]);
            acc[r][1] = fmaf(t1.x, w4.y, acc[r][1]);
            acc[r][2] = fmaf(t1.x, w4.z, acc[r][2]);
            acc[r][3] = fmaf(t1.x, w4.w, acc[r][3]);
            acc[r][0] = fmaf(t1.y, w5.x, acc[r][0]);
            acc[r][1] = fmaf(t1.y, w5.y, acc[r][1]);
            acc[r][2] = fmaf(t1.y, w5.z, acc[r][2]);
            acc[r][3] = fmaf(t1.y, w5.w, acc[r][3]);
            acc[r][0] = fmaf(t1.z, w6.x, acc[r][0]);
            acc[r][1] = fmaf(t1.z, w6.y, acc[r][1]);
            acc[r][2] = fmaf(t1.z, w6.z, acc[r][2]);
            acc[r][3] = fmaf(t1.z, w6.w, acc[r][3]);
            acc[r][0] = fmaf(t1.w, w7.x, acc[r][0]);
            acc[r][1] = fmaf(t1.w, w7.y, acc[r][1]);
            acc[r][2] = fmaf(t1.w, w7.z, acc[r][2]);
            acc[r][3] = fmaf(t1.w, w7.w, acc[r][3]);
        }
    }
}

__device__ __forceinline__ void store4f(float* dst, float a, float b, float c, float d) {
    *(float4*)dst = make_float4(a, b, c, d);
}

extern "C" __global__ __launch_bounds__(256, 3)
void k_mlp(const float* __restrict__ invar, const float* __restrict__ features,
           const float* __restrict__ iW1, const float* __restrict__ ib1,
           const float* __restrict__ iW2, const float* __restrict__ ib2,
           const float* __restrict__ fW1, const float* __restrict__ fb1,
           const float* __restrict__ fW2, const float* __restrict__ fb2,
           const float* __restrict__ sW1, const float* __restrict__ sb1,
           const float* __restrict__ sW2, const float* __restrict__ sb2,
           const float* __restrict__ gW, const float* __restrict__ gb,
           float* __restrict__ out) {
    const int TILE = 32;
    const int pt0 = blockIdx.x * TILE;
    const int tid = threadIdx.x;
    const int cg = tid & 31, pg = tid >> 5;
    const int c0 = cg * 4, p0 = pg * 4;

    // LDS budget ~51.3 KB -> 3 blocks/CU.
    __shared__ __align__(16) float shin[TILE * 260];   // concat(inv_h, feat_h); also hosts features tile
    __shared__ __align__(16) float bufA[TILE * 132];   // hidden scratch
    __shared__ __align__(16) float inv6[TILE * 8];     // invariants tile
    __shared__ float sc[TILE];

    {   // load invariants tile (32 x 8, padded)
        int p = tid >> 3, j = tid & 7;
        inv6[p * 8 + j] = invar[(size_t)(pt0 + p) * 8 + j];
    }
#pragma unroll
    for (int it = 0; it < 8; it++) {   // features tile (32 x 64) -> shin[:,128:192] (lifetime-disjoint)
        int idx = tid + it * 256;
        int p = idx >> 6, f = idx & 63;
        shin[p * 260 + 128 + f] = features[(size_t)(pt0 + p) * FF + f];
    }
    if (tid < TILE) sc[tid] = gb[0];
    __syncthreads();

    float acc[4][4];

    // L1a: gelu(inv @ iW1 + ib1) -> bufA
    gemm_small<6, 8>(inv6, iW1, ib1, p0, c0, acc);
#pragma unroll
    for (int i = 0; i < 4; i++)
        store4f(&bufA[(p0 + i) * 132 + c0], gelu_exact(acc[i][0]), gelu_exact(acc[i][1]),
                gelu_exact(acc[i][2]), gelu_exact(acc[i][3]));
    __syncthreads();

    // L2a: bufA @ iW2 + ib2 -> shin[:, 0:128]
    gemm_c8<128, 132>(bufA, iW2, ib2, p0, c0, acc);
#pragma unroll
    for (int i = 0; i < 4; i++)
        store4f(&shin[(p0 + i) * 260 + c0], acc[i][0], acc[i][1], acc[i][2], acc[i][3]);
    __syncthreads();

    // L1b: gelu(feat @ fW1 + fb1) -> bufA   (features live at shin[:,128:192])
    gemm_c8<64, 260>(shin + 128, fW1, fb1, p0, c0, acc);
#pragma unroll
    for (int i = 0; i < 4; i++)
        store4f(&bufA[(p0 + i) * 132 + c0], gelu_exact(acc[i][0]), gelu_exact(acc[i][1]),
                gelu_exact(acc[i][2]), gelu_exact(acc[i][3]));
    __syncthreads();

    // L2b: bufA @ fW2 + fb2 -> shin[:, 128:256]  (overwrites features tile - done with it)
    gemm_c8<128, 132>(bufA, fW2, fb2, p0, c0, acc);
#pragma unroll
    for (int i = 0; i < 4; i++)
        store4f(&shin[(p0 + i) * 260 + 128 + c0], acc[i][0], acc[i][1], acc[i][2], acc[i][3]);
    __syncthreads();

    // L1c: gelu(shin @ sW1 + sb1) -> bufA
    gemm_c8<256, 260>(shin, sW1, sb1, p0, c0, acc);
#pragma unroll
    for (int i = 0; i < 4; i++)
        store4f(&bufA[(p0 + i) * 132 + c0], gelu_exact(acc[i][0]), gelu_exact(acc[i][1]),
                gelu_exact(acc[i][2]), gelu_exact(acc[i][3]));
    __syncthreads();

    // L2c: bufA @ sW2 + sb2 (in regs), then scalar = hidden @ g0_W + g0_b
    gemm_c8<128, 132>(bufA, sW2, sb2, p0, c0, acc);
    float4 g = *(const float4*)(gW + c0);
#pragma unroll
    for (int i = 0; i < 4; i++) {
        float s = acc[i][0] * g.x + acc[i][1] * g.y + acc[i][2] * g.z + acc[i][3] * g.w;
        atomicAdd(&sc[p0 + i], s);
    }
    __syncthreads();
    if (tid < TILE) out[(size_t)(pt0 + tid) * 16] = sc[tid];
}

// ---------------- launcher ----------------
extern "C" void kernel_launch(void* const* d_in, const int* in_sizes, int n_in,
                              void* d_out, int out_size, void* d_ws, size_t ws_size,
                              hipStream_t stream) {
    const float* coords   = (const float*)d_in[0];
    const float* features = (const float*)d_in[1];
    const float* iW1 = (const float*)d_in[2],  * ib1 = (const float*)d_in[3];
    const float* iW2 = (const float*)d_in[4],  * ib2 = (const float*)d_in[5];
    const float* fW1 = (const float*)d_in[6],  * fb1 = (const float*)d_in[7];
    const float* fW2 = (const float*)d_in[8],  * fb2 = (const float*)d_in[9];
    const float* sW1 = (const float*)d_in[10], * sb1 = (const float*)d_in[11];
    const float* sW2 = (const float*)d_in[12], * sb2 = (const float*)d_in[13];
    const float* gW  = (const float*)d_in[14], * gb  = (const float*)d_in[15];
    float* out = (float*)d_out;

    float* ws = (float*)d_ws;
    float4* coords4 = (float4*)ws;            // B*N float4
    float* center = ws + BB * NN * 4;         // B*4 floats
    float* invar  = center + 32;              // B*N*8 floats

    hipLaunchKernelGGL(k_prep, dim3(BB), dim3(256), 0, stream, coords, coords4, center);
    hipLaunchKernelGGL(k_knn, dim3(1024), dim3(256), 0, stream, coords4, center, invar, out);
    hipLaunchKernelGGL(k_mlp, dim3(1024), dim3(256), 0, stream, invar, features,
                       iW1, ib1, iW2, ib2, fW1, fb1, fW2, fb2, sW1, sb1, sW2, sb2, gW, gb, out);
}

// Round 9
// 332.670 us; speedup vs baseline: 17.7776x; 17.7776x over previous
//
#include <hip/hip_runtime.h>
#include <hip/hip_bf16.h>

#define BB 8
#define NN 4096
#define FF 64
#define HH 128
#define KNN 16

// ---- reference-matching arithmetic (XLA-CPU style: FMA-contracted dot/sq) ----
__device__ __forceinline__ float sq3(float x, float y, float z) {
    return fmaf(z, z, fmaf(y, y, __fmul_rn(x, x)));
}
// dist2 = (sq_n + sq_m) - 2*dot, dot = fma chain
__device__ __forceinline__ float dist2f(float px, float py, float pz, float psq, float4 cc) {
    float t = fmaf(pz, cc.z, fmaf(py, cc.y, __fmul_rn(px, cc.x)));
    return __fsub_rn(__fadd_rn(psq, cc.w), __fmul_rn(2.0f, t));
}

// ---------------- Kernel 1: pack coords + sq norm, compute per-batch center ----------------
extern "C" __global__ __launch_bounds__(256)
void k_prep(const float* __restrict__ coords, float4* __restrict__ coords4, float* __restrict__ center) {
    const int b = blockIdx.x, tid = threadIdx.x;
    __shared__ float rx[256], ry[256], rz[256];
    float sx = 0.f, sy = 0.f, sz = 0.f;
    for (int n = tid; n < NN; n += 256) {
        const float* c = coords + (size_t)(b * NN + n) * 3;
        float x = c[0], y = c[1], z = c[2];
        coords4[b * NN + n] = make_float4(x, y, z, sq3(x, y, z));
        sx += x; sy += y; sz += z;
    }
    rx[tid] = sx; ry[tid] = sy; rz[tid] = sz;
    __syncthreads();
    for (int s = 128; s > 0; s >>= 1) {
        if (tid < s) { rx[tid] += rx[tid + s]; ry[tid] += ry[tid + s]; rz[tid] += rz[tid + s]; }
        __syncthreads();
    }
    if (tid == 0) {
        center[b * 4 + 0] = rx[0] * (1.0f / NN);
        center[b * 4 + 1] = ry[0] * (1.0f / NN);
        center[b * 4 + 2] = rz[0] * (1.0f / NN);
    }
}

// Jacobi rotation on symmetric 3x3 (exact rotations, division-safe).
#define JROT(app, aqq, apq, arp, arq, vp0, vp1, vp2, vq0, vq1, vq2) { \
    float tau_ = (aqq - app) / (2.0f * apq); \
    float tt_ = copysignf(1.0f, tau_) / (fabsf(tau_) + sqrtf(1.0f + tau_ * tau_)); \
    if (apq == 0.0f) tt_ = 0.0f; \
    float cc_ = 1.0f / sqrtf(1.0f + tt_ * tt_); \
    float ss_ = tt_ * cc_; \
    float app_n = cc_*cc_*app - 2.0f*cc_*ss_*apq + ss_*ss_*aqq; \
    float aqq_n = ss_*ss_*app + 2.0f*cc_*ss_*apq + cc_*cc_*aqq; \
    float apq_n = cc_*ss_*(app - aqq) + (cc_*cc_ - ss_*ss_)*apq; \
    float arp_n = cc_*arp - ss_*arq; \
    float arq_n = ss_*arp + cc_*arq; \
    app = app_n; aqq = aqq_n; apq = apq_n; arp = arp_n; arq = arq_n; \
    float t0_ = cc_*vp0 - ss_*vq0, t1_ = cc_*vp1 - ss_*vq1, t2_ = cc_*vp2 - ss_*vq2; \
    vq0 = ss_*vp0 + cc_*vq0; vq1 = ss_*vp1 + cc_*vq1; vq2 = ss_*vp2 + cc_*vq2; \
    vp0 = t0_; vp1 = t1_; vp2 = t2_; }

#define SWAPF(a, b) { float sw_ = a; a = b; b = sw_; }

// Bitonic sort 16 floats ascending (80 compare-exchanges, exact multiset op).
__device__ __forceinline__ void sort16(float (&d)[16]) {
#pragma unroll
    for (int k = 2; k <= 16; k <<= 1) {
#pragma unroll
        for (int j = k >> 1; j > 0; j >>= 1) {
#pragma unroll
            for (int i = 0; i < 16; i++) {
                int l = i ^ j;
                if (l > i) {
                    if ((i & k) == 0) {
                        float mn = fminf(d[i], d[l]);
                        d[l] = fmaxf(d[i], d[l]);
                        d[i] = mn;
                    } else {
                        float mx = fmaxf(d[i], d[l]);
                        d[l] = fminf(d[i], d[l]);
                        d[i] = mx;
                    }
                }
            }
        }
    }
}

// dk (asc) + d (asc) -> dk = 16 smallest of the 32, ascending (Batcher halver + clean).
__device__ __forceinline__ void merge16(float (&dk)[16], const float (&d)[16]) {
    float t[16];
#pragma unroll
    for (int i = 0; i < 16; i++) t[i] = fminf(dk[i], d[15 - i]);   // bitonic, holds lowest 16
#pragma unroll
    for (int j = 8; j > 0; j >>= 1) {
#pragma unroll
        for (int i = 0; i < 16; i++) {
            int l = i ^ j;
            if (l > i) {
                float mn = fminf(t[i], t[l]);
                t[l] = fmaxf(t[i], t[l]);
                t[i] = mn;
            }
        }
    }
#pragma unroll
    for (int i = 0; i < 16; i++) dk[i] = t[i];
}

// ---------------- Kernel 2: kNN + local geometry + non-MLP output channels ----------------
// 1024 blocks x 256 threads. Block: batch b = blk>>7, 32-point chunk (blk&127).
// Thread: point = chunk*32 + (tid&31), candidate-eighth h = tid>>5 (512 candidates each).
extern "C" __global__ __launch_bounds__(256, 4)
void k_knn(const float4* __restrict__ coords4, const float* __restrict__ center,
           float* __restrict__ invar, float* __restrict__ out) {
    const int blk = blockIdx.x;
    const int b = blk >> 7;
    const int chunk = blk & 127;
    const int tid = threadIdx.x;
    const int pid = tid & 31;
    const int h = tid >> 5;
    const int n = chunk * 32 + pid;
    const float4* __restrict__ C = coords4 + b * NN;

    __shared__ __align__(16) float4 tile[512];    // 64 cands per eighth, 8 KB
    __shared__ int ilist[256 * 24];               // per (point,eighth): 15 strict + 8 tie + pad (24 KB)
    __shared__ int cnts[256];                     // packed cs | ct<<8
    float* mb = (float*)ilist;                    // merge buffer (256*17 floats), lifetime-disjoint

    float4 me = C[n];
    const float px = me.x, py = me.y, pz = me.z, psq = me.w;
    const float INF = __builtin_inff();

    // ---- pass 1: per-eighth sorted top-16 values via batch-sort + network merge ----
    float dk[KNN];
#pragma unroll
    for (int i = 0; i < KNN; i++) dk[i] = INF;

    for (int r = 0; r < 8; r++) {
        __syncthreads();
#pragma unroll
        for (int e = tid; e < 512; e += 256) {
            int seg = e >> 6, idx = e & 63;
            tile[e] = C[seg * 512 + r * 64 + idx];
        }
        __syncthreads();
        const float4* T = &tile[h * 64];
        const int selfj = n - (h * 512 + r * 64);   // in [0,64) iff diagonal in this slice
#pragma unroll
        for (int bt = 0; bt < 4; bt++) {
            float d[16];
#pragma unroll
            for (int i = 0; i < 16; i++) {
                float4 cc = T[bt * 16 + i];          // near-uniform -> LDS broadcast
                float dd = dist2f(px, py, pz, psq, cc);
                d[i] = (bt * 16 + i) == selfj ? INF : dd;
            }
            sort16(d);
            merge16(dk, d);
        }
    }

    // ---- symmetric 8-way merge: every thread merges its 7 partners' sorted-16 ----
    __syncthreads();
#pragma unroll
    for (int i = 0; i < KNN; i++) mb[tid * 17 + i] = dk[i];
    __syncthreads();
#pragma unroll
    for (int p = 1; p < 8; p++) {
        const int partner = (((h + p) & 7) << 5) + pid;
        float o[16];
#pragma unroll
        for (int i = 0; i < KNN; i++) o[i] = mb[partner * 17 + i];
        merge16(dk, o);
    }
    const float d15 = dk[15];

    // ---- pass 2: per-eighth index collection (strict < d15; ties == d15, index order) ----
    int cs = 0, ct = 0;
    const int lbase = (pid * 8 + h) * 24;
    for (int r = 0; r < 8; r++) {
        __syncthreads();
#pragma unroll
        for (int e = tid; e < 512; e += 256) {
            int seg = e >> 6, idx = e & 63;
            tile[e] = C[seg * 512 + r * 64 + idx];
        }
        __syncthreads();
        const float4* T = &tile[h * 64];
        const int base = h * 512 + r * 64;
#pragma unroll 4
        for (int j = 0; j < 64; j++) {
            float4 cc = T[j];
            float d = dist2f(px, py, pz, psq, cc);   // bitwise identical to pass 1
            int g = base + j;
            if (g != n && d <= d15) {
                if (d < d15) {
                    if (cs < 15) ilist[lbase + cs] = g;
                    cs++;
                } else if (ct < 8) {
                    ilist[lbase + 15 + ct] = g;
                    ct++;
                }
            }
        }
    }
    cnts[pid * 8 + h] = (cs & 0xff) | (ct << 8);
    __syncthreads();

    if (h != 0) return;   // first 32 threads handle the 32 points' epilogue

    // ---- assemble exactly 16 neighbor ids: stricts (segment order = index order), then ties ----
    int s[8], t8[8], sb[8], tb[8], cum[8], tcum[8];
#pragma unroll
    for (int q = 0; q < 8; q++) {
        int cp = cnts[pid * 8 + q];
        s[q] = cp & 0xff; t8[q] = cp >> 8;
        sb[q] = (pid * 8 + q) * 24; tb[q] = sb[q] + 15;
    }
    cum[0] = s[0]; tcum[0] = t8[0];
#pragma unroll
    for (int q = 1; q < 8; q++) { cum[q] = cum[q - 1] + s[q]; tcum[q] = tcum[q - 1] + t8[q]; }

    float cxx = 0.f, cxy = 0.f, cxz = 0.f, cyy = 0.f, cyz = 0.f, czz = 0.f, radsum = 0.f;
#pragma unroll
    for (int j = 0; j < KNN; j++) {
        int addr = sb[0] + j;
#pragma unroll
        for (int q = 1; q < 8; q++)
            if (j >= cum[q - 1]) addr = sb[q] + (j - cum[q - 1]);
        int jt = j - cum[7];
        if (j >= cum[7]) addr = tb[0] + jt;
#pragma unroll
        for (int q = 1; q < 8; q++)
            if (j >= cum[7] && jt >= tcum[q - 1]) addr = tb[q] + (jt - tcum[q - 1]);
        int id = ilist[addr];
        float4 cc = C[id];
        float rx = __fsub_rn(cc.x, px), ry = __fsub_rn(cc.y, py), rz = __fsub_rn(cc.z, pz);
        cxx = __fadd_rn(cxx, __fmul_rn(rx, rx));
        cxy = __fadd_rn(cxy, __fmul_rn(rx, ry));
        cxz = __fadd_rn(cxz, __fmul_rn(rx, rz));
        cyy = __fadd_rn(cyy, __fmul_rn(ry, ry));
        cyz = __fadd_rn(cyz, __fmul_rn(ry, rz));
        czz = __fadd_rn(czz, __fmul_rn(rz, rz));
        float rr = __fadd_rn(__fadd_rn(__fmul_rn(rx, rx), __fmul_rn(ry, ry)), __fmul_rn(rz, rz));
        radsum = __fadd_rn(radsum, sqrtf(rr));
    }
    const float inv_k = 1.0f / KNN;  // exact power of two
    float a00 = cxx * inv_k, a01 = cxy * inv_k, a02 = cxz * inv_k;
    float a11 = cyy * inv_k, a12 = cyz * inv_k, a22 = czz * inv_k;

    // ---- Jacobi eigensolver, 6 cyclic sweeps ----
    float V00 = 1.f, V01 = 0.f, V02 = 0.f;
    float V10 = 0.f, V11 = 1.f, V12 = 0.f;
    float V20 = 0.f, V21 = 0.f, V22 = 1.f;
    for (int sweep = 0; sweep < 6; sweep++) {
        JROT(a00, a11, a01, a02, a12, V00, V10, V20, V01, V11, V21);
        JROT(a00, a22, a02, a01, a12, V00, V10, V20, V02, V12, V22);
        JROT(a11, a22, a12, a01, a02, V01, V11, V21, V02, V12, V22);
    }
    float e0 = a00, e1 = a11, e2 = a22;
    float x0 = V00, y0 = V10, z0 = V20;
    float x1 = V01, y1 = V11, z1 = V21;
    float x2 = V02, y2 = V12, z2 = V22;
    if (e0 > e1) { SWAPF(e0, e1); SWAPF(x0, x1); SWAPF(y0, y1); SWAPF(z0, z1); }
    if (e1 > e2) { SWAPF(e1, e2); SWAPF(x1, x2); SWAPF(y1, y2); SWAPF(z1, z2); }
    if (e0 > e1) { SWAPF(e0, e1); SWAPF(x0, x1); SWAPF(y0, y1); SWAPF(z0, z1); }

    // ---- orient + normalize normal (col 0 = smallest eigenvalue) ----
    float cx = center[b * 4 + 0], cy = center[b * 4 + 1], cz = center[b * 4 + 2];
    float ox = __fsub_rn(px, cx), oy = __fsub_rn(py, cy), oz = __fsub_rn(pz, cz);
    float dt = __fadd_rn(__fadd_rn(__fmul_rn(x0, ox), __fmul_rn(y0, oy)), __fmul_rn(z0, oz));
    float sgn = (dt >= 0.0f) ? 1.0f : -1.0f;
    x0 *= sgn; y0 *= sgn; z0 *= sgn;
    float nrm = sqrtf(__fadd_rn(__fadd_rn(__fmul_rn(x0, x0), __fmul_rn(y0, y0)), __fmul_rn(z0, z0)));
    float den = fmaxf(nrm, 1e-6f);
    x0 = x0 / den; y0 = y0 / den; z0 = z0 / den;

    // ---- invariants -> ws ----
    float radius = radsum * inv_k;
    float crad = sqrtf(__fadd_rn(__fadd_rn(__fmul_rn(ox, ox), __fmul_rn(oy, oy)), __fmul_rn(oz, oz)));
    float esum = fmaxf(__fadd_rn(__fadd_rn(e0, e1), e2), 1e-6f);
    float dom = e2 / esum;
    float* ip = invar + (size_t)(b * NN + n) * 8;
    ip[0] = e0; ip[1] = e1; ip[2] = e2; ip[3] = radius; ip[4] = crad; ip[5] = dom;
    ip[6] = 0.f; ip[7] = 0.f;

    // ---- output channels (f32). ch0 placeholder, overwritten by k_mlp ----
    float pd = __fadd_rn(__fadd_rn(__fmul_rn(px, x0), __fmul_rn(py, y0)), __fmul_rn(pz, z0));
    float4* o = (float4*)(out + (size_t)(b * NN + n) * 16);
    o[0] = make_float4(0.0f, x0, y0, -z0);
    o[1] = make_float4(-pd, x0, y0, z0);
    o[2] = make_float4(0.0f, 0.0f, 0.0f, px);
    o[3] = make_float4(py, pz, 1.0f, 0.0f);
}

// ---------------- Kernel 3: fused MLPs ----------------
__device__ __forceinline__ float gelu_exact(float x) {
    return 0.5f * x * (1.0f + erff(x * 0.70710678118654752440f));
}

// Small-K GEMM (K=6).
template <int KDIM, int LDA>
__device__ __forceinline__ void gemm_small(const float* __restrict__ A, const float* __restrict__ W,
                                           const float* __restrict__ bias, int p0, int c0, float acc[4][4]) {
    float4 bb = *(const float4*)(bias + c0);
#pragma unroll
    for (int i = 0; i < 4; i++) { acc[i][0] = bb.x; acc[i][1] = bb.y; acc[i][2] = bb.z; acc[i][3] = bb.w; }
#pragma unroll
    for (int k = 0; k < KDIM; k++) {
        float4 w = *(const float4*)(W + k * HH + c0);
#pragma unroll
        for (int i = 0; i < 4; i++) {
            float a = A[(p0 + i) * LDA + k];
            acc[i][0] = fmaf(a, w.x, acc[i][0]);
            acc[i][1] = fmaf(a, w.y, acc[i][1]);
            acc[i][2] = fmaf(a, w.z, acc[i][2]);
            acc[i][3] = fmaf(a, w.w, acc[i][3]);
        }
    }
}

// K%8==0 GEMM. Chunk-8 batch of W loads inside a NOT-unrolled loop.
// R7/R8 lesson: full unroll of this loop lets the scheduler hoist load batches
// across chunks -> register blowup -> scratch spill (FETCH 6MB -> 10.5GB, 35x slowdown).
// #pragma unroll 1 keeps the body a loop; 8 W loads amortize latency within a chunk.
// Accumulation order: ascending k per output (bitwise identical to gemm_small).
template <int KDIM, int LDA>
__device__ __forceinline__ void gemm_c8(const float* __restrict__ A, const float* __restrict__ W,
                                        const float* __restrict__ bias, int p0, int c0, float acc[4][4]) {
    static_assert(KDIM % 8 == 0, "KDIM must be a multiple of 8");
    float4 bb = *(const float4*)(bias + c0);
#pragma unroll
    for (int i = 0; i < 4; i++) { acc[i][0] = bb.x; acc[i][1] = bb.y; acc[i][2] = bb.z; acc[i][3] = bb.w; }

#pragma unroll 1
    for (int kk = 0; kk < KDIM; kk += 8) {
        const float* Wk = W + kk * HH + c0;
        float4 w0 = *(const float4*)(Wk + 0 * HH);
        float4 w1 = *(const float4*)(Wk + 1 * HH);
        float4 w2 = *(const float4*)(Wk + 2 * HH);
        float4 w3 = *(const float4*)(Wk + 3 * HH);
        float4 w4 = *(const float4*)(Wk + 4 * HH);
        float4 w5 = *(const float4*)(Wk + 5 * HH);
        float4 w6 = *(const float4*)(Wk + 6 * HH);
        float4 w7 = *(const float4*)(Wk + 7 * HH);
#pragma unroll
        for (int r = 0; r < 4; r++) {
            const float* Ar = A + (p0 + r) * LDA + kk;
            float4 t0 = *(const float4*)(Ar);
            float4 t1 = *(const float4*)(Ar + 4);
            acc[r][0] = fmaf(t0.x, w0.x, acc[r][0]);
            acc[r][1] = fmaf(t0.x, w0.y, acc[r][1]);
            acc[r][2] = fmaf(t0.x, w0.z, acc[r][2]);
            acc[r][3] = fmaf(t0.x, w0.w, acc[r][3]);
            acc[r][0] = fmaf(t0.y, w1.x, acc[r][0]);
            acc[r][1] = fmaf(t0.y, w1.y, acc[r][1]);
            acc[r][2] = fmaf(t0.y, w1.z, acc[r][2]);
            acc[r][3] = fmaf(t0.y, w1.w, acc[r][3]);
            acc[r][0] = fmaf(t0.z, w2.x, acc[r][0]);
            acc[r][1] = fmaf(t0.z, w2.y, acc[r][1]);
            acc[r][2] = fmaf(t0.z, w2.z, acc[r][2]);
            acc[r][3] = fmaf(t0.z, w2.w, acc[r][3]);
            acc[r][0] = fmaf(t0.w, w3.x, acc[r][0]);
            acc[r][1] = fmaf(t0.w, w3.y, acc[r][1]);
            acc[r][2] = fmaf(t0.w, w3.z, acc[r][2]);
            acc[r][3] = fmaf(t0.w, w3.w, acc[r][3]);
            acc[r][0] = fmaf(t1.x, w4.x, acc[r][0]);
            acc[r][1] = fmaf(t1.x, w4.y, acc[r][1]);
            acc[r][2] = fmaf(t1.x, w4.z, acc[r][2]);
            acc[r][3] = fmaf(t1.x, w4.w, acc[r][3]);
            acc[r][0] = fmaf(t1.y, w5.x, acc[r][0]);
            acc[r][1] = fmaf(t1.y, w5.y, acc[r][1]);
            acc[r][2] = fmaf(t1.y, w5.z, acc[r][2]);
            acc[r][3] = fmaf(t1.y, w5.w, acc[r][3]);
            acc[r][0] = fmaf(t1.z, w6.x, acc[r][0]);
            acc[r][1] = fmaf(t1.z, w6.y, acc[r][1]);
            acc[r][2] = fmaf(t1.z, w6.z, acc[r][2]);
            acc[r][3] = fmaf(t1.z, w6.w, acc[r][3]);
            acc[r][0] = fmaf(t1.w, w7.x, acc[r][0]);
            acc[r][1] = fmaf(t1.w, w7.y, acc[r][1]);
            acc[r][2] = fmaf(t1.w, w7.z, acc[r][2]);
            acc[r][3] = fmaf(t1.w, w7.w, acc[r][3]);
        }
    }
}

__device__ __forceinline__ void store4f(float* dst, float a, float b, float c, float d) {
    *(float4*)dst = make_float4(a, b, c, d);
}

extern "C" __global__ __launch_bounds__(256, 3)
void k_mlp(const float* __restrict__ invar, const float* __restrict__ features,
           const float* __restrict__ iW1, const float* __restrict__ ib1,
           const float* __restrict__ iW2, const float* __restrict__ ib2,
           const float* __restrict__ fW1, const float* __restrict__ fb1,
           const float* __restrict__ fW2, const float* __restrict__ fb2,
           const float* __restrict__ sW1, const float* __restrict__ sb1,
           const float* __restrict__ sW2, const float* __restrict__ sb2,
           const float* __restrict__ gW, const float* __restrict__ gb,
           float* __restrict__ out) {
    const int TILE = 32;
    const int pt0 = blockIdx.x * TILE;
    const int tid = threadIdx.x;
    const int cg = tid & 31, pg = tid >> 5;
    const int c0 = cg * 4, p0 = pg * 4;

    // LDS budget ~51.3 KB -> 3 blocks/CU.
    __shared__ __align__(16) float shin[TILE * 260];   // concat(inv_h, feat_h); also hosts features tile
    __shared__ __align__(16) float bufA[TILE * 132];   // hidden scratch
    __shared__ __align__(16) float inv6[TILE * 8];     // invariants tile
    __shared__ float sc[TILE];

    {   // load invariants tile (32 x 8, padded)
        int p = tid >> 3, j = tid & 7;
        inv6[p * 8 + j] = invar[(size_t)(pt0 + p) * 8 + j];
    }
#pragma unroll
    for (int it = 0; it < 8; it++) {   // features tile (32 x 64) -> shin[:,128:192] (lifetime-disjoint)
        int idx = tid + it * 256;
        int p = idx >> 6, f = idx & 63;
        shin[p * 260 + 128 + f] = features[(size_t)(pt0 + p) * FF + f];
    }
    if (tid < TILE) sc[tid] = gb[0];
    __syncthreads();

    float acc[4][4];

    // L1a: gelu(inv @ iW1 + ib1) -> bufA
    gemm_small<6, 8>(inv6, iW1, ib1, p0, c0, acc);
#pragma unroll
    for (int i = 0; i < 4; i++)
        store4f(&bufA[(p0 + i) * 132 + c0], gelu_exact(acc[i][0]), gelu_exact(acc[i][1]),
                gelu_exact(acc[i][2]), gelu_exact(acc[i][3]));
    __syncthreads();

    // L2a: bufA @ iW2 + ib2 -> shin[:, 0:128]
    gemm_c8<128, 132>(bufA, iW2, ib2, p0, c0, acc);
#pragma unroll
    for (int i = 0; i < 4; i++)
        store4f(&shin[(p0 + i) * 260 + c0], acc[i][0], acc[i][1], acc[i][2], acc[i][3]);
    __syncthreads();

    // L1b: gelu(feat @ fW1 + fb1) -> bufA   (features live at shin[:,128:192])
    gemm_c8<64, 260>(shin + 128, fW1, fb1, p0, c0, acc);
#pragma unroll
    for (int i = 0; i < 4; i++)
        store4f(&bufA[(p0 + i) * 132 + c0], gelu_exact(acc[i][0]), gelu_exact(acc[i][1]),
                gelu_exact(acc[i][2]), gelu_exact(acc[i][3]));
    __syncthreads();

    // L2b: bufA @ fW2 + fb2 -> shin[:, 128:256]  (overwrites features tile - done with it)
    gemm_c8<128, 132>(bufA, fW2, fb2, p0, c0, acc);
#pragma unroll
    for (int i = 0; i < 4; i++)
        store4f(&shin[(p0 + i) * 260 + 128 + c0], acc[i][0], acc[i][1], acc[i][2], acc[i][3]);
    __syncthreads();

    // L1c: gelu(shin @ sW1 + sb1) -> bufA
    gemm_c8<256, 260>(shin, sW1, sb1, p0, c0, acc);
#pragma unroll
    for (int i = 0; i < 4; i++)
        store4f(&bufA[(p0 + i) * 132 + c0], gelu_exact(acc[i][0]), gelu_exact(acc[i][1]),
                gelu_exact(acc[i][2]), gelu_exact(acc[i][3]));
    __syncthreads();

    // L2c: bufA @ sW2 + sb2 (in regs), then scalar = hidden @ g0_W + g0_b
    gemm_c8<128, 132>(bufA, sW2, sb2, p0, c0, acc);
    float4 g = *(const float4*)(gW + c0);
#pragma unroll
    for (int i = 0; i < 4; i++) {
        float s = acc[i][0] * g.x + acc[i][1] * g.y + acc[i][2] * g.z + acc[i][3] * g.w;
        atomicAdd(&sc[p0 + i], s);
    }
    __syncthreads();
    if (tid < TILE) out[(size_t)(pt0 + tid) * 16] = sc[tid];
}

// ---------------- launcher ----------------
extern "C" void kernel_launch(void* const* d_in, const int* in_sizes, int n_in,
                              void* d_out, int out_size, void* d_ws, size_t ws_size,
                              hipStream_t stream) {
    const float* coords   = (const float*)d_in[0];
    const float* features = (const float*)d_in[1];
    const float* iW1 = (const float*)d_in[2],  * ib1 = (const float*)d_in[3];
    const float* iW2 = (const float*)d_in[4],  * ib2 = (const float*)d_in[5];
    const float* fW1 = (const float*)d_in[6],  * fb1 = (const float*)d_in[7];
    const float* fW2 = (const float*)d_in[8],  * fb2 = (const float*)d_in[9];
    const float* sW1 = (const float*)d_in[10], * sb1 = (const float*)d_in[11];
    const float* sW2 = (const float*)d_in[12], * sb2 = (const float*)d_in[13];
    const float* gW  = (const float*)d_in[14], * gb  = (const float*)d_in[15];
    float* out = (float*)d_out;

    float* ws = (float*)d_ws;
    float4* coords4 = (float4*)ws;            // B*N float4
    float* center = ws + BB * NN * 4;         // B*4 floats
    float* invar  = center + 32;              // B*N*8 floats

    hipLaunchKernelGGL(k_prep, dim3(BB), dim3(256), 0, stream, coords, coords4, center);
    hipLaunchKernelGGL(k_knn, dim3(1024), dim3(256), 0, stream, coords4, center, invar, out);
    hipLaunchKernelGGL(k_mlp, dim3(1024), dim3(256), 0, stream, invar, features,
                       iW1, ib1, iW2, ib2, fW1, fb1, fW2, fb2, sW1, sb1, sW2, sb2, gW, gb, out);
}